// Round 1
// baseline (91.293 us; speedup 1.0000x reference)
//
#include <hip/hip_runtime.h>
#include <hip/hip_bf16.h>
#include <cstdint>

// NT-Xent contrastive loss, B=4096, D=128, T=0.1.
// loss = sum_i [ log(sum_{j!=i} exp(s_ij)) - s_{i,partner(i)} ] * (B/2)
// s_ij = 10 * cos(n_i, n_j).  We store n * sqrt(10*log2e) in bf16 so the
// MFMA accumulator is directly the exp2 argument (s * log2e).

typedef __bf16 bf16x8 __attribute__((ext_vector_type(8)));
typedef __bf16 bf16x2 __attribute__((ext_vector_type(2)));
typedef float  f32x4  __attribute__((ext_vector_type(4)));

#define NROWS 8192
#define DIM   128
#define ALPHA 3.7982827f            /* sqrt(10 * log2(e)) */
#define LN2   0.6931471805599453f

// ---- async global->LDS, 16B per lane, wave-uniform LDS base ----
__device__ __forceinline__ void load_lds16(const void* g, void* l) {
    __builtin_amdgcn_global_load_lds(
        (const __attribute__((address_space(1))) unsigned int*)(uintptr_t)g,
        (__attribute__((address_space(3))) unsigned int*)(uintptr_t)l,
        16, 0, 0);
}

// K-chunk xor swizzle: element k of row r stored at chunk c' = (c&8)|((c^r)&7),
// c = k>>3.  Keeps ds_read_b128 fragment reads at free 2-way bank conflicts,
// while remaining a contiguous-per-row layout (global_load_lds compatible).

// ---------------- Kernel A: normalize + scale + swizzle + zero ws ----------
__global__ __launch_bounds__(256) void norm_kernel(
    const float* __restrict__ out1, const float* __restrict__ out2,
    __bf16* __restrict__ nb, float* __restrict__ rowsum, float* __restrict__ dout)
{
    const int t = threadIdx.x, lane = t & 63, wid = t >> 6;
    const int row = blockIdx.x * 4 + wid;
    const float* src = (row < 4096) ? (out1 + (size_t)row * DIM)
                                    : (out2 + (size_t)(row - 4096) * DIM);
    float2 v = ((const float2*)src)[lane];
    float ss = v.x * v.x + v.y * v.y;
    #pragma unroll
    for (int off = 1; off < 64; off <<= 1) ss += __shfl_xor(ss, off);
    const float s = rsqrtf(ss) * ALPHA;

    const int c  = lane >> 2;                      // chunk of element 2*lane
    const int cs = (c & 8) | ((c ^ row) & 7);
    const int idx = row * DIM + cs * 8 + ((2 * lane) & 7);
    bf16x2 w;
    w.x = (__bf16)(v.x * s);
    w.y = (__bf16)(v.y * s);
    *(bf16x2*)(nb + idx) = w;

    if (blockIdx.x < 32) rowsum[blockIdx.x * 256 + t] = 0.0f;
    if (blockIdx.x == 0 && t == 0) dout[0] = 0.0f;
}

// ---------------- Kernel B: Gram + exp + per-row sums ----------------------
// grid (64, 8): block = rows [rb*128,+128) x cols [cb*1024,+1024).
// 4 waves in 2x2; each wave owns a 64x64 output tile per 128-col iteration.
// A-strip fragments register-resident (K=128 fits); B-tiles via global_load_lds.
__global__ __launch_bounds__(256, 2) void simloss_main(
    const __bf16* __restrict__ nb, float* __restrict__ rowsum)
{
    __shared__ __bf16 Bsm[128 * DIM];             // 32 KB
    const int t = threadIdx.x, lane = t & 63, wid = t >> 6;
    const int quad = lane >> 4, l15 = lane & 15;
    const int rb = blockIdx.x, cb = blockIdx.y;
    const int rowbase = rb * 128 + (wid & 1) * 64;   // global row of wave tile
    const int ncol0   = (wid >> 1) * 64;             // col offset inside B tile

    // swizzled chunk byte/element offsets per k-step
    int cso[4];
    #pragma unroll
    for (int k = 0; k < 4; ++k) {
        int c = k * 4 + quad;
        cso[k] = ((c & 8) | ((c ^ lane) & 7)) * 8;   // lane&7 == row&7 here
    }

    // A fragments from global (L2-hot), 16 x 16B per lane
    bf16x8 afrag[4][4];
    #pragma unroll
    for (int mt = 0; mt < 4; ++mt) {
        const __bf16* ar = nb + (size_t)(rowbase + mt * 16 + l15) * DIM;
        #pragma unroll
        for (int k = 0; k < 4; ++k) afrag[mt][k] = *(const bf16x8*)(ar + cso[k]);
    }

    float rowpart[4][4] = {};

    for (int ct = 0; ct < 8; ++ct) {
        __syncthreads();
        // stage 128 cols (= 128 contiguous rows of nb) into LDS: 32 KB
        const char* gB = (const char*)(nb + (size_t)(cb * 1024 + ct * 128) * DIM);
        char* lB = (char*)Bsm + wid * 1024;
        const char* gBw = gB + wid * 1024 + lane * 16;
        #pragma unroll
        for (int i = 0; i < 8; ++i) load_lds16(gBw + i * 4096, lB + i * 4096);
        __syncthreads();

        f32x4 acc[4][4] = {};
        #pragma unroll
        for (int k = 0; k < 4; ++k) {
            bf16x8 b[4];
            #pragma unroll
            for (int nt = 0; nt < 4; ++nt)
                b[nt] = *(const bf16x8*)(Bsm + (ncol0 + nt * 16 + l15) * DIM + cso[k]);
            #pragma unroll
            for (int mt = 0; mt < 4; ++mt)
                #pragma unroll
                for (int nt = 0; nt < 4; ++nt)
                    acc[mt][nt] = __builtin_amdgcn_mfma_f32_16x16x32_bf16(
                        afrag[mt][k], b[nt], acc[mt][nt], 0, 0, 0);
        }

        // epilogue: acc is already s*log2e -> single v_exp_f32 each
        #pragma unroll
        for (int mt = 0; mt < 4; ++mt)
            #pragma unroll
            for (int nt = 0; nt < 4; ++nt)
                #pragma unroll
                for (int r = 0; r < 4; ++r)
                    rowpart[mt][r] += __builtin_amdgcn_exp2f(acc[mt][nt][r]);
    }

    // reduce the 16 lanes sharing a quad (cols), one atomic per row
    #pragma unroll
    for (int mt = 0; mt < 4; ++mt)
        #pragma unroll
        for (int r = 0; r < 4; ++r) {
            float v = rowpart[mt][r];
            v += __shfl_xor(v, 1);
            v += __shfl_xor(v, 2);
            v += __shfl_xor(v, 4);
            v += __shfl_xor(v, 8);
            if (l15 == 0)
                atomicAdd(&rowsum[rowbase + mt * 16 + quad * 4 + r], v);
        }
}

// ---------------- Kernel C: subtract diag, logs, positive pairs, reduce ----
__global__ __launch_bounds__(256) void finalize_kernel(
    const __bf16* __restrict__ nb, const float* __restrict__ rowsum,
    float* __restrict__ dout)
{
    const int t = threadIdx.x, lane = t & 63, wid = t >> 6;
    const int w = blockIdx.x * 4 + wid;            // 512 waves, 16 rows each
    float wacc = 0.0f;
    for (int rr = 0; rr < 16; ++rr) {
        const int i = w * 16 + rr;
        const int p = i ^ 4096;                    // partner row (B=4096, pow2)
        // rows i and p share (row&7) so the k-swizzle cancels in the dot
        bf16x2 av = *(const bf16x2*)(nb + (size_t)i * DIM + 2 * lane);
        bf16x2 bv = *(const bf16x2*)(nb + (size_t)p * DIM + 2 * lane);
        float ax = (float)av.x, ay = (float)av.y;
        float bx = (float)bv.x, by = (float)bv.y;
        float self = ax * ax + ay * ay;            // -> 10*log2e exactly as MFMA saw it
        float pos  = ax * bx + ay * by;            // s_pos * log2e
        #pragma unroll
        for (int off = 1; off < 64; off <<= 1) {
            self += __shfl_xor(self, off);
            pos  += __shfl_xor(pos, off);
        }
        if (lane == 0) {
            float se = rowsum[i] - __builtin_amdgcn_exp2f(self);  // drop diagonal
            wacc += logf(se) - pos * LN2;          // lse_nat - s_pos_nat
        }
    }
    if (lane == 0) atomicAdd(dout, wacc * 2048.0f); // * B/2
}

extern "C" void kernel_launch(void* const* d_in, const int* in_sizes, int n_in,
                              void* d_out, int out_size, void* d_ws, size_t ws_size,
                              hipStream_t stream)
{
    const float* out1 = (const float*)d_in[0];
    const float* out2 = (const float*)d_in[1];
    __bf16* nb     = (__bf16*)d_ws;                               // 2 MB
    float*  rowsum = (float*)((char*)d_ws + (size_t)NROWS * DIM * 2); // 32 KB
    float*  dout   = (float*)d_out;

    hipLaunchKernelGGL(norm_kernel, dim3(2048), dim3(256), 0, stream,
                       out1, out2, nb, rowsum, dout);
    hipLaunchKernelGGL(simloss_main, dim3(64, 8), dim3(256), 0, stream,
                       (const __bf16*)nb, rowsum);
    hipLaunchKernelGGL(finalize_kernel, dim3(128), dim3(256), 0, stream,
                       (const __bf16*)nb, rowsum, dout);
}